// Round 3
// baseline (1638.037 us; speedup 1.0000x reference)
//
#include <hip/hip_runtime.h>
#include <hip/hip_fp16.h>
#include <stdint.h>

typedef _Float16 f16;
typedef _Float16 f16x8 __attribute__((ext_vector_type(8)));
typedef float    f32x16 __attribute__((ext_vector_type(16)));
typedef unsigned int u32x2 __attribute__((ext_vector_type(2)));

#define NEDGE 1000000
#define NT    31250        // 32-edge tiles, exact
#define NTHR  512
#define GRID  512
#define GW    (GRID*8)     // total waves

// ---- fragment-space weight layout in d_ws (f16 elems) ----
// frag = 64 lanes x 8 f16 = 512 elems. Global frag index f enumerates:
//   W1: nt(4) x ks(17)  -> 68 frags   (ks16 = bias column)
//   W2: nt(8) x ks(9)   -> 72 frags
//   W3: nt(2) x ks(17)  -> 34 frags
//   W4: ks(5)           -> 5 frags
#define F1 68
#define F2 (F1+72)
#define F3 (F2+34)
#define FTOT (F3+5)              // 179 frags
#define WS_WBYTES (FTOT*512*2)   // 183296 B
#define ZUOFF  WS_WBYTES
#define ZBOFF  (ZUOFF + 100000*128*2)
#define WS_FULL (ZBOFF + 100000*128*2)   // 51383296 B

// ---------------- weight fragment builder ----------------
// frag value: A[i=n][k] for swapped MFMA: lane&31 = n (row), k = (lane>>5)*8 + e
__global__ __launch_bounds__(512) void wfrag_kernel(
    const float* __restrict__ W1, const float* __restrict__ b1,
    const float* __restrict__ W2, const float* __restrict__ b2,
    const float* __restrict__ W3, const float* __restrict__ b3,
    const float* __restrict__ W4, const float* __restrict__ b4,
    f16* __restrict__ ws)
{
    int tid = blockIdx.x*512 + threadIdx.x;
    if (tid >= FTOT*64) return;
    int f = tid >> 6, lane = tid & 63;
    int li = lane & 31, hi = lane >> 5;
    f16 v[8];
    if (f < F1) {
        int nt = f/17, ks = f%17, n = nt*32 + li;
        #pragma unroll
        for (int e = 0; e < 8; ++e)
            v[e] = (ks < 16) ? (f16)W1[n*256 + ks*16 + hi*8 + e]
                             : (f16)((e==0 && hi==0) ? b1[n] : 0.f);
    } else if (f < F2) {
        int g = f-F1, nt = g/9, ks = g%9, n = nt*32 + li;
        #pragma unroll
        for (int e = 0; e < 8; ++e)
            v[e] = (ks < 8) ? (f16)W2[n*128 + ks*16 + hi*8 + e]
                            : (f16)((e==0 && hi==0) ? b2[n] : 0.f);
    } else if (f < F3) {
        int g = f-F2, nt = g/17, ks = g%17, n = nt*32 + li;
        #pragma unroll
        for (int e = 0; e < 8; ++e)
            v[e] = (ks < 16) ? (f16)W3[n*256 + ks*16 + hi*8 + e]
                             : (f16)((e==0 && hi==0) ? b3[n] : 0.f);
    } else {
        int ks = f-F3, n = li; bool ok = n < 5;
        #pragma unroll
        for (int e = 0; e < 8; ++e)
            v[e] = (ks < 4) ? (ok ? (f16)W4[n*64 + ks*16 + hi*8 + e] : (f16)0.f)
                            : (f16)((e==0 && hi==0 && ok) ? b4[n] : 0.f);
    }
    f16* d = ws + (size_t)f*512 + lane*8;
    #pragma unroll
    for (int e = 0; e < 8; ++e) d[e] = v[e];
}

// ---------------- embedding f32 -> f16 ----------------
__device__ __forceinline__ void cvt8(const float* __restrict__ s, f16* __restrict__ d) {
    float4 a = ((const float4*)s)[0], b = ((const float4*)s)[1];
    union { f16 h[8]; uint4 u; } r;
    r.h[0]=(f16)a.x; r.h[1]=(f16)a.y; r.h[2]=(f16)a.z; r.h[3]=(f16)a.w;
    r.h[4]=(f16)b.x; r.h[5]=(f16)b.y; r.h[6]=(f16)b.z; r.h[7]=(f16)b.w;
    *(uint4*)d = r.u;
}
__global__ __launch_bounds__(512) void ecvt_kernel(
    const float* __restrict__ zu, const float* __restrict__ zb,
    f16* __restrict__ du, f16* __restrict__ db)
{
    const int NPER = 100000*128/8;   // 1.6M chunks per table
    int i = blockIdx.x*512 + threadIdx.x;
    if (i < NPER)            cvt8(zu + (size_t)i*8, du + (size_t)i*8);
    else if (i < 2*NPER)   { int j = i - NPER; cvt8(zb + (size_t)j*8, db + (size_t)j*8); }
}

// ---- RNE pack two f32 -> one dword of 2 f16 ----
__device__ __forceinline__ unsigned int pkrne(float v0, float v1) {
    union { f16 h[2]; unsigned int u; } r;
    r.h[0] = (f16)v0; r.h[1] = (f16)v1; return r.u;
}

// ---- epilogue: acc (D of swapped 32x32 MFMA, this ntile) -> 2 kstep B-frags ----
// D: lane&31 = edge, n_local = (reg&3) + 8*(reg>>2) + 4*(lane>>5)
// B-frag(ks parity p): dwords [A'0, A'1, B'0, B'1] where (A',B') = permlane32_swap(P[2p], P[2p+1])
template<bool RELU>
__device__ __forceinline__ void epi(const f32x16& a, f16x8* f0, f16x8* f1) {
    unsigned int P[4][2];
    #pragma unroll
    for (int q = 0; q < 4; ++q)
        #pragma unroll
        for (int dd = 0; dd < 2; ++dd) {
            float v0 = a[4*q + 2*dd], v1 = a[4*q + 2*dd + 1];
            if (RELU) { v0 = fmaxf(v0, 0.f); v1 = fmaxf(v1, 0.f); }
            P[q][dd] = pkrne(v0, v1);
        }
    #pragma unroll
    for (int p = 0; p < 2; ++p) {
        u32x2 r0 = __builtin_amdgcn_permlane32_swap(P[2*p][0], P[2*p+1][0], false, false);
        u32x2 r1 = __builtin_amdgcn_permlane32_swap(P[2*p][1], P[2*p+1][1], false, false);
        union { unsigned int u[4]; f16x8 v; } fb;
        fb.u[0] = r0[0]; fb.u[1] = r1[0]; fb.u[2] = r0[1]; fb.u[3] = r1[1];
        if (p == 0) *f0 = fb.v; else *f1 = fb.v;
    }
}

// ---------------- fused streaming edge MLP ----------------
// 512 thr = 8 waves; W1+W3 staged to LDS once (one barrier), then each wave
// independently streams 32-edge tiles: gather -> L1..L4 -> store. No barriers.
template<bool EF16>
__global__ __launch_bounds__(NTHR, 2) void edge_mlp(
    const int* __restrict__ eli,
    const float* __restrict__ zu, const float* __restrict__ zb,
    const f16* __restrict__ zu16, const f16* __restrict__ zb16,
    const f16* __restrict__ wsw, float* __restrict__ out)
{
    __shared__ f16 sW1[F1*512];          // 69632 B
    __shared__ f16 sW3[34*512];          // 34816 B

    const int tid  = threadIdx.x;
    const int lane = tid & 63;
    const int li   = lane & 31;
    const int hi   = lane >> 5;

    // ---- stage W1 frags (4352 uint4 chunks) + W3 frags (2176 chunks) ----
    {
        const uint4* ws4 = (const uint4*)wsw;
        #pragma unroll
        for (int i = 0; i < 9; ++i) {
            int c = i*NTHR + tid;
            if (c < F1*64) ((uint4*)sW1)[c] = ws4[c];
        }
        const uint4* w3s = ws4 + F2*64;
        #pragma unroll
        for (int i = 0; i < 5; ++i) {
            int c = i*NTHR + tid;
            if (c < 34*64) ((uint4*)sW3)[c] = w3s[c];
        }
    }
    __syncthreads();   // only barrier in the kernel

    // ---- per-wave setup ----
    const bool idx64 = __all(eli[2*lane + 1] == 0);
    const f16x8* w2g = (const f16x8*)wsw + F1*64;      // W2 frags, frag-linear
    const f16x8* w4g = (const f16x8*)wsw + F3*64;      // W4 frags
    f16x8 w4f[5];
    #pragma unroll
    for (int ks = 0; ks < 5; ++ks) w4f[ks] = w4g[ks*64 + lane];

    f16x8 onef = {};                  // bias-column B-frag: 1.0 at k==first, hi==0
    if (hi == 0) onef[0] = (f16)1.f;

    const int gw = (blockIdx.x*NTHR + tid) >> 6;

    f16x8 za[16];
    int t = gw;
    if (t < NT) {       // preload first tile's gather
        int e = t*32 + li;
        int ru = idx64 ? eli[2*e]           : eli[e];
        int rb = idx64 ? eli[2*(NEDGE + e)] : eli[NEDGE + e];
        if (EF16) {
            const f16x8* ur = (const f16x8*)(zu16 + (size_t)ru*128);
            const f16x8* br = (const f16x8*)(zb16 + (size_t)rb*128);
            #pragma unroll
            for (int ks = 0; ks < 8; ++ks) { za[ks] = ur[ks*2 + hi]; za[8+ks] = br[ks*2 + hi]; }
        } else {
            const float4* ur = (const float4*)(zu + (size_t)ru*128);
            const float4* br = (const float4*)(zb + (size_t)rb*128);
            #pragma unroll
            for (int ks = 0; ks < 8; ++ks) {
                float4 a = ur[ks*4 + hi*2], b = ur[ks*4 + hi*2 + 1];
                union { unsigned int u[4]; f16x8 v; } z;
                z.u[0]=pkrne(a.x,a.y); z.u[1]=pkrne(a.z,a.w); z.u[2]=pkrne(b.x,b.y); z.u[3]=pkrne(b.z,b.w);
                za[ks] = z.v;
                a = br[ks*4 + hi*2]; b = br[ks*4 + hi*2 + 1];
                z.u[0]=pkrne(a.x,a.y); z.u[1]=pkrne(a.z,a.w); z.u[2]=pkrne(b.x,b.y); z.u[3]=pkrne(b.z,b.w);
                za[8+ks] = z.v;
            }
        }
    }

    for (; t < NT; t += GW) {
        // ---- prefetch next tile's indices (latency hidden under L1) ----
        int tn = t + GW, run = 0, rbn = 0;
        if (tn < NT) {
            int e2 = tn*32 + li;
            run = idx64 ? eli[2*e2]            : eli[e2];
            rbn = idx64 ? eli[2*(NEDGE + e2)]  : eli[NEDGE + e2];
        }

        // ---- layer 1: h1[e][128] = relu(z @ W1^T + b1), swapped MFMA ----
        f16x8 h1f[8];
        #pragma unroll
        for (int nt = 0; nt < 4; ++nt) {
            f32x16 a = {};
            #pragma unroll
            for (int ks = 0; ks < 17; ++ks) {
                f16x8 af = *(const f16x8*)(sW1 + ((nt*17 + ks) << 9) + (lane << 3));
                f16x8 bf = (ks < 16) ? za[ks] : onef;
                a = __builtin_amdgcn_mfma_f32_32x32x16_f16(af, bf, a, 0, 0, 0);
            }
            epi<true>(a, &h1f[2*nt], &h1f[2*nt+1]);
        }

        // ---- issue next tile's gather into za (overlaps L2/L3/L4) ----
        if (tn < NT) {
            if (EF16) {
                const f16x8* ur = (const f16x8*)(zu16 + (size_t)run*128);
                const f16x8* br = (const f16x8*)(zb16 + (size_t)rbn*128);
                #pragma unroll
                for (int ks = 0; ks < 8; ++ks) { za[ks] = ur[ks*2 + hi]; za[8+ks] = br[ks*2 + hi]; }
            } else {
                const float4* ur = (const float4*)(zu + (size_t)run*128);
                const float4* br = (const float4*)(zb + (size_t)rbn*128);
                #pragma unroll
                for (int ks = 0; ks < 8; ++ks) {
                    float4 a = ur[ks*4 + hi*2], b = ur[ks*4 + hi*2 + 1];
                    union { unsigned int u[4]; f16x8 v; } z;
                    z.u[0]=pkrne(a.x,a.y); z.u[1]=pkrne(a.z,a.w); z.u[2]=pkrne(b.x,b.y); z.u[3]=pkrne(b.z,b.w);
                    za[ks] = z.v;
                    a = br[ks*4 + hi*2]; b = br[ks*4 + hi*2 + 1];
                    z.u[0]=pkrne(a.x,a.y); z.u[1]=pkrne(a.z,a.w); z.u[2]=pkrne(b.x,b.y); z.u[3]=pkrne(b.z,b.w);
                    za[8+ks] = z.v;
                }
            }
        }

        // ---- layer 2 (N=256, two halves) fused with layer-3 partial accumulation ----
        f32x16 acc3[2] = { {}, {} };
        #pragma unroll
        for (int h = 0; h < 2; ++h) {
            f16x8 h2f[8];
            #pragma unroll
            for (int nt2 = 0; nt2 < 4; ++nt2) {
                int nt = h*4 + nt2;
                f32x16 a = {};
                #pragma unroll
                for (int ks = 0; ks < 9; ++ks) {
                    f16x8 af = w2g[(nt*9 + ks)*64 + lane];
                    f16x8 bf = (ks < 8) ? h1f[ks] : onef;
                    a = __builtin_amdgcn_mfma_f32_32x32x16_f16(af, bf, a, 0, 0, 0);
                }
                epi<true>(a, &h2f[2*nt2], &h2f[2*nt2+1]);
            }
            #pragma unroll
            for (int n3 = 0; n3 < 2; ++n3)
                #pragma unroll
                for (int ksl = 0; ksl < 8; ++ksl) {
                    f16x8 af = *(const f16x8*)(sW3 + ((n3*17 + h*8 + ksl) << 9) + (lane << 3));
                    acc3[n3] = __builtin_amdgcn_mfma_f32_32x32x16_f16(af, h2f[ksl], acc3[n3], 0, 0, 0);
                }
        }
        // L3 bias column
        #pragma unroll
        for (int n3 = 0; n3 < 2; ++n3) {
            f16x8 af = *(const f16x8*)(sW3 + ((n3*17 + 16) << 9) + (lane << 3));
            acc3[n3] = __builtin_amdgcn_mfma_f32_32x32x16_f16(af, onef, acc3[n3], 0, 0, 0);
        }

        // ---- layer 3 epilogue -> h3 frags; layer 4 + store ----
        f16x8 h3f[4];
        epi<true>(acc3[0], &h3f[0], &h3f[1]);
        epi<true>(acc3[1], &h3f[2], &h3f[3]);

        f32x16 a4 = {};
        #pragma unroll
        for (int ks = 0; ks < 5; ++ks)
            a4 = __builtin_amdgcn_mfma_f32_32x32x16_f16(w4f[ks], (ks < 4) ? h3f[ks] : onef, a4, 0, 0, 0);

        size_t eb = (size_t)(t*32 + li)*5;
        if (hi == 0) { out[eb+0]=a4[0]; out[eb+1]=a4[1]; out[eb+2]=a4[2]; out[eb+3]=a4[3]; }
        else         { out[eb+4]=a4[0]; }
    }
}

extern "C" void kernel_launch(void* const* d_in, const int* in_sizes, int n_in,
                              void* d_out, int out_size, void* d_ws, size_t ws_size,
                              hipStream_t stream) {
    const float* zu  = (const float*)d_in[0];
    const float* zb  = (const float*)d_in[1];
    const int*   eli = (const int*)d_in[2];
    const float* W1  = (const float*)d_in[3];
    const float* b1  = (const float*)d_in[4];
    const float* W2  = (const float*)d_in[5];
    const float* b2  = (const float*)d_in[6];
    const float* W3  = (const float*)d_in[7];
    const float* b3  = (const float*)d_in[8];
    const float* W4  = (const float*)d_in[9];
    const float* b4  = (const float*)d_in[10];
    float* out = (float*)d_out;

    f16* wsw  = (f16*)d_ws;
    f16* zu16 = (f16*)((char*)d_ws + ZUOFF);
    f16* zb16 = (f16*)((char*)d_ws + ZBOFF);

    wfrag_kernel<<<(FTOT*64 + 511)/512, 512, 0, stream>>>(W1,b1,W2,b2,W3,b3,W4,b4, wsw);

    if (ws_size >= (size_t)WS_FULL) {
        ecvt_kernel<<<(2*(100000*128/8) + 511)/512, 512, 0, stream>>>(zu, zb, zu16, zb16);
        edge_mlp<true><<<GRID, NTHR, 0, stream>>>(eli, zu, zb, zu16, zb16, wsw, out);
    } else {
        edge_mlp<false><<<GRID, NTHR, 0, stream>>>(eli, zu, zb, zu16, zb16, wsw, out);
    }
}

// Round 4
// 1457.488 us; speedup vs baseline: 1.1239x; 1.1239x over previous
//
#include <hip/hip_runtime.h>
#include <hip/hip_fp16.h>
#include <stdint.h>

typedef _Float16 f16;
typedef _Float16 f16x8 __attribute__((ext_vector_type(8)));
typedef float    f32x16 __attribute__((ext_vector_type(16)));
typedef unsigned int u32x2 __attribute__((ext_vector_type(2)));

#define NEDGE 1000000
#define NT    31250        // 32-edge tiles, exact (31250*32 = 1e6)
#define NTHR  512
#define GRID  256
#define GW    (GRID*8)     // total waves = 2048

// ---- fragment-space weight layout in d_ws (f16 elems) ----
// frag = 64 lanes x 8 f16 = 512 elems. Global frag index f enumerates:
//   W1: nt(4) x ks(17)  -> 68 frags   (ks16 = bias column)
//   W2: nt(8) x ks(9)   -> 72 frags
//   W3: nt(2) x ks(17)  -> 34 frags
//   W4: ks(5)           -> 5 frags
#define F1 68
#define F2 (F1+72)
#define F3 (F2+34)
#define FTOT (F3+5)              // 179 frags
#define WS_WBYTES (FTOT*512*2)
#define ZUOFF  WS_WBYTES
#define ZBOFF  (ZUOFF + 100000*128*2)
#define WS_FULL (ZBOFF + 100000*128*2)

// ---------------- weight fragment builder (verified R3) ----------------
// frag value: A[i=n][k] for swapped MFMA: lane&31 = n (row), k = (lane>>5)*8 + e
__global__ __launch_bounds__(512) void wfrag_kernel(
    const float* __restrict__ W1, const float* __restrict__ b1,
    const float* __restrict__ W2, const float* __restrict__ b2,
    const float* __restrict__ W3, const float* __restrict__ b3,
    const float* __restrict__ W4, const float* __restrict__ b4,
    f16* __restrict__ ws)
{
    int tid = blockIdx.x*512 + threadIdx.x;
    if (tid >= FTOT*64) return;
    int f = tid >> 6, lane = tid & 63;
    int li = lane & 31, hi = lane >> 5;
    f16 v[8];
    if (f < F1) {
        int nt = f/17, ks = f%17, n = nt*32 + li;
        #pragma unroll
        for (int e = 0; e < 8; ++e)
            v[e] = (ks < 16) ? (f16)W1[n*256 + ks*16 + hi*8 + e]
                             : (f16)((e==0 && hi==0) ? b1[n] : 0.f);
    } else if (f < F2) {
        int g = f-F1, nt = g/9, ks = g%9, n = nt*32 + li;
        #pragma unroll
        for (int e = 0; e < 8; ++e)
            v[e] = (ks < 8) ? (f16)W2[n*128 + ks*16 + hi*8 + e]
                            : (f16)((e==0 && hi==0) ? b2[n] : 0.f);
    } else if (f < F3) {
        int g = f-F2, nt = g/17, ks = g%17, n = nt*32 + li;
        #pragma unroll
        for (int e = 0; e < 8; ++e)
            v[e] = (ks < 16) ? (f16)W3[n*256 + ks*16 + hi*8 + e]
                             : (f16)((e==0 && hi==0) ? b3[n] : 0.f);
    } else {
        int ks = f-F3, n = li; bool ok = n < 5;
        #pragma unroll
        for (int e = 0; e < 8; ++e)
            v[e] = (ks < 4) ? (ok ? (f16)W4[n*64 + ks*16 + hi*8 + e] : (f16)0.f)
                            : (f16)((e==0 && hi==0 && ok) ? b4[n] : 0.f);
    }
    f16* d = ws + (size_t)f*512 + lane*8;
    #pragma unroll
    for (int e = 0; e < 8; ++e) d[e] = v[e];
}

// ---------------- embedding f32 -> f16 ----------------
__device__ __forceinline__ void cvt8(const float* __restrict__ s, f16* __restrict__ d) {
    float4 a = ((const float4*)s)[0], b = ((const float4*)s)[1];
    union { f16 h[8]; uint4 u; } r;
    r.h[0]=(f16)a.x; r.h[1]=(f16)a.y; r.h[2]=(f16)a.z; r.h[3]=(f16)a.w;
    r.h[4]=(f16)b.x; r.h[5]=(f16)b.y; r.h[6]=(f16)b.z; r.h[7]=(f16)b.w;
    *(uint4*)d = r.u;
}
__global__ __launch_bounds__(512) void ecvt_kernel(
    const float* __restrict__ zu, const float* __restrict__ zb,
    f16* __restrict__ du, f16* __restrict__ db)
{
    const int NPER = 100000*128/8;
    int i = blockIdx.x*512 + threadIdx.x;
    if (i < NPER)            cvt8(zu + (size_t)i*8, du + (size_t)i*8);
    else if (i < 2*NPER)   { int j = i - NPER; cvt8(zb + (size_t)j*8, db + (size_t)j*8); }
}

// ---- RNE pack two f32 -> one dword of 2 f16 ----
__device__ __forceinline__ unsigned int pkrne(float v0, float v1) {
    union { f16 h[2]; unsigned int u; } r;
    r.h[0] = (f16)v0; r.h[1] = (f16)v1; return r.u;
}

// ---- epilogue fragment builder, BY VALUE (no address-taken arrays) ----
// From D of swapped 32x32 MFMA (lane&31=edge, n_local=(reg&3)+8*(reg>>2)+4*hi),
// produce the kstep-parity-P B-frag via RNE pack + permlane32_swap. Verified R3.
template<bool RELU, int P>
__device__ __forceinline__ f16x8 mkfrag(f32x16 a) {
    float x0=a[8*P+0], x1=a[8*P+1], x2=a[8*P+2], x3=a[8*P+3];
    float y0=a[8*P+4], y1=a[8*P+5], y2=a[8*P+6], y3=a[8*P+7];
    if (RELU) {
        x0=fmaxf(x0,0.f); x1=fmaxf(x1,0.f); x2=fmaxf(x2,0.f); x3=fmaxf(x3,0.f);
        y0=fmaxf(y0,0.f); y1=fmaxf(y1,0.f); y2=fmaxf(y2,0.f); y3=fmaxf(y3,0.f);
    }
    unsigned int pa0 = pkrne(x0,x1), pa1 = pkrne(x2,x3);
    unsigned int pb0 = pkrne(y0,y1), pb1 = pkrne(y2,y3);
    u32x2 r0 = __builtin_amdgcn_permlane32_swap(pa0, pb0, false, false);
    u32x2 r1 = __builtin_amdgcn_permlane32_swap(pa1, pb1, false, false);
    union { unsigned int u[4]; f16x8 v; } fb;
    fb.u[0] = r0[0]; fb.u[1] = r1[0]; fb.u[2] = r0[1]; fb.u[3] = r1[1];
    return fb.v;
}

#define MFMA(A,B,C) __builtin_amdgcn_mfma_f32_32x32x16_f16((A),(B),(C),0,0,0)
#define LDW1(idx) (*(const f16x8*)(sW1 + ((idx) << 9) + (lane << 3)))
#define LDW3(idx) (*(const f16x8*)(sW3 + ((idx) << 9) + (lane << 3)))
// compile-time select of h1/h2 fragment (folds under #pragma unroll)
#define SEL8(k, v0,v1,v2,v3,v4,v5,v6,v7, deflt) \
    ((k)==0?(v0):(k)==1?(v1):(k)==2?(v2):(k)==3?(v3): \
     (k)==4?(v4):(k)==5?(v5):(k)==6?(v6):(k)==7?(v7):(deflt))

// ---------------- fused streaming edge MLP ----------------
// 512 thr = 8 waves; W1+W3 staged to LDS once (one barrier), then each wave
// independently streams 32-edge tiles: gather -> L1..L4 -> store. No barriers,
// no spills: all inter-layer state in named SSA f16x8 fragments.
template<bool EF16>
__global__ __launch_bounds__(NTHR, 2) void edge_mlp(
    const int* __restrict__ eli,
    const float* __restrict__ zu, const float* __restrict__ zb,
    const f16* __restrict__ zu16, const f16* __restrict__ zb16,
    const f16* __restrict__ wsw, float* __restrict__ out)
{
    __shared__ f16 sW1[F1*512];          // 69632 B
    __shared__ f16 sW3[34*512];          // 34816 B

    const int tid  = threadIdx.x;
    const int lane = tid & 63;
    const int li   = lane & 31;
    const int hi   = lane >> 5;

    // ---- stage W1 + W3 frags to LDS (frag-linear, conflict-free) ----
    {
        const uint4* ws4 = (const uint4*)wsw;
        #pragma unroll
        for (int i = 0; i < 9; ++i) {
            int c = i*NTHR + tid;
            if (c < F1*64) ((uint4*)sW1)[c] = ws4[c];
        }
        const uint4* w3s = ws4 + F2*64;
        #pragma unroll
        for (int i = 0; i < 5; ++i) {
            int c = i*NTHR + tid;
            if (c < 34*64) ((uint4*)sW3)[c] = w3s[c];
        }
    }
    __syncthreads();   // only barrier in the kernel

    const bool idx64 = __all(eli[2*lane + 1] == 0);
    const f16x8* w2g = (const f16x8*)wsw + F1*64;      // W2 frags, frag-linear
    const f16x8* w4g = (const f16x8*)wsw + F3*64;      // W4 frags
    const f16x8 w4f0 = w4g[0*64 + lane], w4f1 = w4g[1*64 + lane],
                w4f2 = w4g[2*64 + lane], w4f3 = w4g[3*64 + lane],
                w4f4 = w4g[4*64 + lane];

    f16x8 onef = {};                  // bias-column B-frag
    if (hi == 0) onef[0] = (f16)1.f;

    const int gw = (blockIdx.x*NTHR + tid) >> 6;

    int t = gw, ru = 0, rb = 0;
    if (t < NT) {
        int e = t*32 + li;
        ru = idx64 ? eli[2*e]           : eli[e];
        rb = idx64 ? eli[2*(NEDGE + e)] : eli[NEDGE + e];
    }

    for (; t < NT; t += GW) {
        // ---- prefetch next tile's indices ----
        int tn = t + GW, run = 0, rbn = 0;
        if (tn < NT) {
            int e2 = tn*32 + li;
            run = idx64 ? eli[2*e2]           : eli[e2];
            rbn = idx64 ? eli[2*(NEDGE + e2)] : eli[NEDGE + e2];
        }

        // ---- layer 1: ks-outer, 4 parallel accumulators; gather frags load
        //      on demand (compiler hoists the 16 independent loads early) ----
        f32x16 a0 = {}, a1 = {}, a2 = {}, a3 = {};
        #pragma unroll
        for (int ks = 0; ks < 17; ++ks) {
            f16x8 bz;
            if (ks == 16) bz = onef;
            else if (EF16) {
                const f16* base = (ks < 8) ? (zu16 + (size_t)ru*128 + ks*16)
                                           : (zb16 + (size_t)rb*128 + (ks-8)*16);
                bz = *(const f16x8*)(base + hi*8);
            } else {
                const float* base = (ks < 8) ? (zu + (size_t)ru*128 + ks*16)
                                             : (zb + (size_t)rb*128 + (ks-8)*16);
                float4 va = *(const float4*)(base + hi*8);
                float4 vb = *(const float4*)(base + hi*8 + 4);
                union { unsigned int u[4]; f16x8 v; } z;
                z.u[0]=pkrne(va.x,va.y); z.u[1]=pkrne(va.z,va.w);
                z.u[2]=pkrne(vb.x,vb.y); z.u[3]=pkrne(vb.z,vb.w);
                bz = z.v;
            }
            a0 = MFMA(LDW1(0*17 + ks), bz, a0);
            a1 = MFMA(LDW1(1*17 + ks), bz, a1);
            a2 = MFMA(LDW1(2*17 + ks), bz, a2);
            a3 = MFMA(LDW1(3*17 + ks), bz, a3);
        }
        const f16x8 h1_0 = mkfrag<true,0>(a0), h1_1 = mkfrag<true,1>(a0);
        const f16x8 h1_2 = mkfrag<true,0>(a1), h1_3 = mkfrag<true,1>(a1);
        const f16x8 h1_4 = mkfrag<true,0>(a2), h1_5 = mkfrag<true,1>(a2);
        const f16x8 h1_6 = mkfrag<true,0>(a3), h1_7 = mkfrag<true,1>(a3);

        // ---- layer 2 (two N-halves) fused with layer-3 accumulation ----
        f32x16 c30 = {}, c31 = {};
        #pragma unroll
        for (int h = 0; h < 2; ++h) {
            f32x16 b0 = {}, b1 = {}, b2 = {}, b3 = {};
            #pragma unroll
            for (int ks = 0; ks < 9; ++ks) {
                f16x8 bf = SEL8(ks, h1_0,h1_1,h1_2,h1_3,h1_4,h1_5,h1_6,h1_7, onef);
                b0 = MFMA(w2g[((h*4+0)*9 + ks)*64 + lane], bf, b0);
                b1 = MFMA(w2g[((h*4+1)*9 + ks)*64 + lane], bf, b1);
                b2 = MFMA(w2g[((h*4+2)*9 + ks)*64 + lane], bf, b2);
                b3 = MFMA(w2g[((h*4+3)*9 + ks)*64 + lane], bf, b3);
            }
            const f16x8 h2_0 = mkfrag<true,0>(b0), h2_1 = mkfrag<true,1>(b0);
            const f16x8 h2_2 = mkfrag<true,0>(b1), h2_3 = mkfrag<true,1>(b1);
            const f16x8 h2_4 = mkfrag<true,0>(b2), h2_5 = mkfrag<true,1>(b2);
            const f16x8 h2_6 = mkfrag<true,0>(b3), h2_7 = mkfrag<true,1>(b3);
            #pragma unroll
            for (int ksl = 0; ksl < 8; ++ksl) {
                f16x8 bf2 = SEL8(ksl, h2_0,h2_1,h2_2,h2_3,h2_4,h2_5,h2_6,h2_7, onef);
                c30 = MFMA(LDW3((0*17 + h*8 + ksl)), bf2, c30);
                c31 = MFMA(LDW3((1*17 + h*8 + ksl)), bf2, c31);
            }
        }
        c30 = MFMA(LDW3(0*17 + 16), onef, c30);
        c31 = MFMA(LDW3(1*17 + 16), onef, c31);

        // ---- layer 3 epilogue -> layer 4 -> store ----
        const f16x8 h3_0 = mkfrag<true,0>(c30), h3_1 = mkfrag<true,1>(c30);
        const f16x8 h3_2 = mkfrag<true,0>(c31), h3_3 = mkfrag<true,1>(c31);

        f32x16 a4 = {};
        a4 = MFMA(w4f0, h3_0, a4);
        a4 = MFMA(w4f1, h3_1, a4);
        a4 = MFMA(w4f2, h3_2, a4);
        a4 = MFMA(w4f3, h3_3, a4);
        a4 = MFMA(w4f4, onef, a4);

        size_t eb = (size_t)(t*32 + li)*5;
        if (hi == 0) { out[eb+0]=a4[0]; out[eb+1]=a4[1]; out[eb+2]=a4[2]; out[eb+3]=a4[3]; }
        else         { out[eb+4]=a4[0]; }

        ru = run; rb = rbn;
    }
}

extern "C" void kernel_launch(void* const* d_in, const int* in_sizes, int n_in,
                              void* d_out, int out_size, void* d_ws, size_t ws_size,
                              hipStream_t stream) {
    const float* zu  = (const float*)d_in[0];
    const float* zb  = (const float*)d_in[1];
    const int*   eli = (const int*)d_in[2];
    const float* W1  = (const float*)d_in[3];
    const float* b1  = (const float*)d_in[4];
    const float* W2  = (const float*)d_in[5];
    const float* b2  = (const float*)d_in[6];
    const float* W3  = (const float*)d_in[7];
    const float* b3  = (const float*)d_in[8];
    const float* W4  = (const float*)d_in[9];
    const float* b4  = (const float*)d_in[10];
    float* out = (float*)d_out;

    f16* wsw  = (f16*)d_ws;
    f16* zu16 = (f16*)((char*)d_ws + ZUOFF);
    f16* zb16 = (f16*)((char*)d_ws + ZBOFF);

    wfrag_kernel<<<(FTOT*64 + 511)/512, 512, 0, stream>>>(W1,b1,W2,b2,W3,b3,W4,b4, wsw);

    if (ws_size >= (size_t)WS_FULL) {
        ecvt_kernel<<<(2*(100000*128/8) + 511)/512, 512, 0, stream>>>(zu, zb, zu16, zb16);
        edge_mlp<true><<<GRID, NTHR, 0, stream>>>(eli, zu, zb, zu16, zb16, wsw, out);
    } else {
        edge_mlp<false><<<GRID, NTHR, 0, stream>>>(eli, zu, zb, zu16, zb16, wsw, out);
    }
}